// Round 1
// baseline (1198.393 us; speedup 1.0000x reference)
//
#include <hip/hip_runtime.h>

typedef __bf16 bf16;
typedef __bf16 bf16x8 __attribute__((ext_vector_type(8)));
typedef __bf16 bf16x4 __attribute__((ext_vector_type(4)));
typedef float  f32x4  __attribute__((ext_vector_type(4)));

// async global->LDS, 16B per lane. LDS dest must be wave-uniform base + lane*16.
__device__ __forceinline__ void gload16(const bf16* g, bf16* l) {
  __builtin_amdgcn_global_load_lds(
      (const __attribute__((address_space(1))) unsigned int*)g,
      (__attribute__((address_space(3))) unsigned int*)l, 16, 0, 0);
}

__device__ __forceinline__ f32x4 mfma16(bf16x8 a, bf16x8 b, f32x4 c) {
  return __builtin_amdgcn_mfma_f32_16x16x32_bf16(a, b, c, 0, 0, 0);
}

__device__ __forceinline__ float gelu_exact(float x) {
  return 0.5f * x * (1.0f + erff(x * 0.70710678118654752f));
}

// ---------------- weight fp32 -> bf16 convert (all 4 weights in one launch) ----
__global__ __launch_bounds__(256, 4)
void cvt_w(const float* __restrict__ a, const float* __restrict__ b,
           const float* __restrict__ c, const float* __restrict__ d,
           bf16* __restrict__ oa, bf16* __restrict__ ob,
           bf16* __restrict__ oc, bf16* __restrict__ od)
{
  int i = blockIdx.x * 256 + threadIdx.x;   // float4 units
  const float* src; bf16* dst;
  if (i < 442368)       { src = a; dst = oa; }
  else if (i < 589824)  { src = b; dst = ob; i -= 442368; }
  else if (i < 1179648) { src = c; dst = oc; i -= 589824; }
  else                  { src = d; dst = od; i -= 1179648; }
  f32x4 v = *(const f32x4*)(src + (size_t)i * 4);
  bf16x4 o;
  #pragma unroll
  for (int jj = 0; jj < 4; ++jj) o[jj] = (bf16)v[jj];
  *(bf16x4*)(dst + (size_t)i * 4) = o;
}

// ---------------- LayerNorm (fp32 in, bf16 out), one block per 768-row --------
__global__ __launch_bounds__(256, 4)
void ln_bf16(const float* __restrict__ x, const float* __restrict__ sc,
             const float* __restrict__ bi, bf16* __restrict__ o)
{
  const int row = blockIdx.x;
  const float* xr = x + (size_t)row * 768;
  const int t = threadIdx.x;
  float v0 = xr[t], v1 = xr[t + 256], v2 = xr[t + 512];
  float s = v0 + v1 + v2;
  float q = v0 * v0 + v1 * v1 + v2 * v2;
  #pragma unroll
  for (int off = 32; off > 0; off >>= 1) { s += __shfl_xor(s, off); q += __shfl_xor(q, off); }
  __shared__ float ls[8];
  const int wv = t >> 6, lane = t & 63;
  if (lane == 0) { ls[wv] = s; ls[wv + 4] = q; }
  __syncthreads();
  s = ls[0] + ls[1] + ls[2] + ls[3];
  q = ls[4] + ls[5] + ls[6] + ls[7];
  const float mean = s * (1.0f / 768.0f);
  const float var  = q * (1.0f / 768.0f) - mean * mean;
  const float rstd = rsqrtf(var + 1e-5f);
  bf16* orow = o + (size_t)row * 768;
  orow[t]       = (bf16)((v0 - mean) * rstd * sc[t]       + bi[t]);
  orow[t + 256] = (bf16)((v1 - mean) * rstd * sc[t + 256] + bi[t + 256]);
  orow[t + 512] = (bf16)((v2 - mean) * rstd * sc[t + 512] + bi[t + 512]);
}

// ---------------- GEMM C[M,N] = A[M,K] * B[N,K]^T  (m97-style 128x128x64) -----
// EPI 0: out bf16 = acc + bias, cols<768 scaled by 0.125 (QKV)
// EPI 1: out f32  = acc + bias + extra (residual add: out-proj, FC2)
// EPI 2: out bf16 = gelu(acc + bias) (FC1)
template<int EPI>
__global__ __launch_bounds__(256, 2)
void gemm_bt(const bf16* __restrict__ A, const bf16* __restrict__ B,
             const float* __restrict__ bias, const float* __restrict__ extra,
             void* __restrict__ outp, int M, int N, int K)
{
  __shared__ bf16 lsA[128 * 64];
  __shared__ bf16 lsB[128 * 64];
  const int tid = threadIdx.x;
  const int lane = tid & 63, w = tid >> 6;
  const int wm = w >> 1, wn = w & 1;
  const long m0 = (long)blockIdx.y * 128, n0 = (long)blockIdx.x * 128;

  f32x4 acc[4][4];
  const f32x4 z = {0.f, 0.f, 0.f, 0.f};
  #pragma unroll
  for (int i = 0; i < 4; ++i)
    #pragma unroll
    for (int j = 0; j < 4; ++j) acc[i][j] = z;

  const int srow = tid >> 3;          // tid*16B / 128B-per-row
  const int scol = (tid & 7) * 8;

  for (int kt = 0; kt < K; kt += 64) {
    #pragma unroll
    for (int i = 0; i < 4; ++i) {
      int row = srow + i * 32;
      gload16(A + (m0 + row) * (long)K + kt + scol, lsA + row * 64 + scol);
      gload16(B + (n0 + row) * (long)K + kt + scol, lsB + row * 64 + scol);
    }
    __syncthreads();   // compiler drains vmcnt before s_barrier -> LDS valid
    #pragma unroll
    for (int kc = 0; kc < 2; ++kc) {
      bf16x8 a[4], b[4];
      #pragma unroll
      for (int i = 0; i < 4; ++i)
        a[i] = *(const bf16x8*)(lsA + (wm * 64 + i * 16 + (lane & 15)) * 64 + kc * 32 + (lane >> 4) * 8);
      #pragma unroll
      for (int j = 0; j < 4; ++j)
        b[j] = *(const bf16x8*)(lsB + (wn * 64 + j * 16 + (lane & 15)) * 64 + kc * 32 + (lane >> 4) * 8);
      #pragma unroll
      for (int i = 0; i < 4; ++i)
        #pragma unroll
        for (int j = 0; j < 4; ++j)
          acc[i][j] = mfma16(a[i], b[j], acc[i][j]);
    }
    __syncthreads();
  }

  #pragma unroll
  for (int i = 0; i < 4; ++i) {
    #pragma unroll
    for (int j = 0; j < 4; ++j) {
      const long gr = m0 + wm * 64 + i * 16 + (lane >> 4) * 4;
      const long gc = n0 + wn * 64 + j * 16 + (lane & 15);
      const float bv = bias[gc];
      #pragma unroll
      for (int r = 0; r < 4; ++r) {
        float v = acc[i][j][r] + bv;
        const long idx = (gr + r) * (long)N + gc;
        if (EPI == 0) {
          if (gc < 768) v *= 0.125f;           // q scaling d^-0.5
          ((bf16*)outp)[idx] = (bf16)v;
        } else if (EPI == 1) {
          ((float*)outp)[idx] = v + extra[idx];
        } else {
          ((bf16*)outp)[idx] = (bf16)gelu_exact(v);
        }
      }
    }
  }
}

// ---------------- V transpose: qkv v-section -> Vt[gh][d][n] ------------------
__global__ __launch_bounds__(256, 4)
void v_transpose(const bf16* __restrict__ qkv, bf16* __restrict__ Vt)
{
  const int nt = blockIdx.x, gh = blockIdx.y;
  const int g = gh / 12, h = gh % 12;
  __shared__ bf16 tile[64][72];
  const int t = threadIdx.x;
  const int nl = t >> 3, d0 = (t & 7) * 8;
  #pragma unroll
  for (int it = 0; it < 2; ++it) {
    int n = nl + it * 32;
    bf16x8 v = *(const bf16x8*)(qkv + (size_t)((nt * 64 + n) * 32 + g) * 2304 + 1536 + h * 64 + d0);
    #pragma unroll
    for (int jj = 0; jj < 8; ++jj) tile[d0 + jj][n] = v[jj];
  }
  __syncthreads();
  const int d = t >> 3, n0 = (t & 7) * 8;
  #pragma unroll
  for (int it = 0; it < 2; ++it) {
    int dd = d + it * 32;
    bf16x8 u = *(const bf16x8*)(&tile[dd][n0]);
    *(bf16x8*)(Vt + (size_t)gh * 32768 + (size_t)dd * 512 + nt * 64 + n0) = u;
  }
}

// ---------------- fused attention: scores+bias+softmax+PV per (g,h,64 q-rows) -
// S stored bf16 in LDS with XOR swizzle byte^=((row&7)<<4); P overwrites S in place.
__global__ __launch_bounds__(256, 1)
void attn_fused(const bf16* __restrict__ qkv, const bf16* __restrict__ Vt,
                const float* __restrict__ bias, bf16* __restrict__ attnout)
{
  const int qt = blockIdx.x, gh = blockIdx.y;
  const int g = gh / 12, h = gh % 12;
  const int q0 = qt * 64;
  const int tid = threadIdx.x, lane = tid & 63, w = tid >> 6;

  __shared__ bf16 lsQ[64 * 64];
  __shared__ bf16 lsKV[2][64 * 64];
  __shared__ bf16 lsS[64 * 512];     // 64KB, swizzled; reused for P

  const int srow = tid >> 3;
  const int scol = (tid & 7) * 8;

  // stage Q tile and K tile 0
  #pragma unroll
  for (int i = 0; i < 2; ++i) {
    int row = srow + i * 32;
    gload16(qkv + (size_t)((q0 + row) * 32 + g) * 2304 + h * 64 + scol, lsQ + row * 64 + scol);
  }
  #pragma unroll
  for (int i = 0; i < 2; ++i) {
    int row = srow + i * 32;
    gload16(qkv + (size_t)(row * 32 + g) * 2304 + 768 + h * 64 + scol, lsKV[0] + row * 64 + scol);
  }
  __syncthreads();

  bf16x8 qa[2];
  #pragma unroll
  for (int kc = 0; kc < 2; ++kc)
    qa[kc] = *(const bf16x8*)(lsQ + (w * 16 + (lane & 15)) * 64 + kc * 32 + (lane >> 4) * 8);

  // ---- phase 1: S = Q*K^T, store bf16 (bias added later in fp32)
  for (int kt = 0; kt < 8; ++kt) {
    if (kt < 7) {
      #pragma unroll
      for (int i = 0; i < 2; ++i) {
        int row = srow + i * 32;
        gload16(qkv + (size_t)(((kt + 1) * 64 + row) * 32 + g) * 2304 + 768 + h * 64 + scol,
                lsKV[(kt + 1) & 1] + row * 64 + scol);
      }
    } else {           // prefetch V tile 0 into buf0 (K tile 6's buffer, already consumed)
      #pragma unroll
      for (int i = 0; i < 2; ++i) {
        int row = srow + i * 32;
        gload16(Vt + (size_t)gh * 32768 + (size_t)row * 512 + scol, lsKV[0] + row * 64 + scol);
      }
    }
    const bf16* lk = lsKV[kt & 1];
    #pragma unroll
    for (int j = 0; j < 4; ++j) {
      bf16x8 b0 = *(const bf16x8*)(lk + (j * 16 + (lane & 15)) * 64 + (lane >> 4) * 8);
      bf16x8 b1 = *(const bf16x8*)(lk + (j * 16 + (lane & 15)) * 64 + 32 + (lane >> 4) * 8);
      f32x4 s = {0.f, 0.f, 0.f, 0.f};
      s = mfma16(qa[0], b0, s);
      s = mfma16(qa[1], b1, s);
      #pragma unroll
      for (int r = 0; r < 4; ++r) {
        int row = w * 16 + (lane >> 4) * 4 + r;
        int col = kt * 64 + j * 16 + (lane & 15);
        int sb = (row * 1024 + col * 2) ^ ((row & 7) << 4);
        *(bf16*)((char*)lsS + sb) = (bf16)s[r];
      }
    }
    __syncthreads();
  }

  // prefetch V tile 1 into buf1 (K tile 7 consumed)
  #pragma unroll
  for (int i = 0; i < 2; ++i) {
    int row = srow + i * 32;
    gload16(Vt + (size_t)gh * 32768 + (size_t)row * 512 + 64 + scol, lsKV[1] + row * 64 + scol);
  }

  // ---- softmax: wave w owns rows w*16..w*16+15; bias streamed with 4-row prefetch
  {
    const int row0 = w * 16;
    const float* bb = bias + ((size_t)gh * 512 + q0 + row0) * 512 + lane * 8;
    f32x4 ba[8], bn[8];
    #pragma unroll
    for (int r = 0; r < 4; ++r) {
      ba[r * 2]     = *(const f32x4*)(bb + (size_t)r * 512);
      ba[r * 2 + 1] = *(const f32x4*)(bb + (size_t)r * 512 + 4);
    }
    for (int c = 0; c < 4; ++c) {
      if (c < 3) {
        #pragma unroll
        for (int r = 0; r < 4; ++r) {
          bn[r * 2]     = *(const f32x4*)(bb + (size_t)((c + 1) * 4 + r) * 512);
          bn[r * 2 + 1] = *(const f32x4*)(bb + (size_t)((c + 1) * 4 + r) * 512 + 4);
        }
      }
      #pragma unroll
      for (int r = 0; r < 4; ++r) {
        const int row = row0 + c * 4 + r;
        const int sb = (row * 1024 + lane * 16) ^ ((row & 7) << 4);
        bf16x8 sv = *(const bf16x8*)((char*)lsS + sb);
        float p[8];
        #pragma unroll
        for (int jj = 0; jj < 8; ++jj)
          p[jj] = (float)sv[jj] + ba[r * 2 + (jj >> 2)][jj & 3];
        float m = p[0];
        #pragma unroll
        for (int jj = 1; jj < 8; ++jj) m = fmaxf(m, p[jj]);
        #pragma unroll
        for (int off = 32; off > 0; off >>= 1) m = fmaxf(m, __shfl_xor(m, off));
        float ssum = 0.f;
        #pragma unroll
        for (int jj = 0; jj < 8; ++jj) { p[jj] = __expf(p[jj] - m); ssum += p[jj]; }
        #pragma unroll
        for (int off = 32; off > 0; off >>= 1) ssum += __shfl_xor(ssum, off);
        const float inv = 1.0f / ssum;
        bf16x8 pv;
        #pragma unroll
        for (int jj = 0; jj < 8; ++jj) pv[jj] = (bf16)(p[jj] * inv);
        *(bf16x8*)((char*)lsS + sb) = pv;      // in-place: all reads precede writes per row
      }
      #pragma unroll
      for (int r8 = 0; r8 < 8; ++r8) ba[r8] = bn[r8];
    }
  }
  __syncthreads();

  // ---- phase 2: O = P * V (V tiles double-buffered, stage after sync)
  f32x4 o[4];
  const f32x4 z = {0.f, 0.f, 0.f, 0.f};
  #pragma unroll
  for (int j = 0; j < 4; ++j) o[j] = z;

  for (int kt = 0; kt < 8; ++kt) {
    bf16x8 pa[2];
    #pragma unroll
    for (int kc = 0; kc < 2; ++kc) {
      int row = w * 16 + (lane & 15);
      int sb = (row * 1024 + kt * 128 + kc * 64 + (lane >> 4) * 16) ^ ((row & 7) << 4);
      pa[kc] = *(const bf16x8*)((char*)lsS + sb);
    }
    const bf16* lv = lsKV[kt & 1];
    #pragma unroll
    for (int j = 0; j < 4; ++j) {
      #pragma unroll
      for (int kc = 0; kc < 2; ++kc) {
        bf16x8 vb = *(const bf16x8*)(lv + (j * 16 + (lane & 15)) * 64 + kc * 32 + (lane >> 4) * 8);
        o[j] = mfma16(pa[kc], vb, o[j]);
      }
    }
    __syncthreads();
    if (kt < 6) {
      #pragma unroll
      for (int i = 0; i < 2; ++i) {
        int row = srow + i * 32;
        gload16(Vt + (size_t)gh * 32768 + (size_t)row * 512 + (kt + 2) * 64 + scol,
                lsKV[kt & 1] + row * 64 + scol);
      }
    }
  }

  #pragma unroll
  for (int j = 0; j < 4; ++j) {
    #pragma unroll
    for (int r = 0; r < 4; ++r) {
      int qrow = q0 + w * 16 + (lane >> 4) * 4 + r;
      int e = h * 64 + j * 16 + (lane & 15);
      attnout[(size_t)(qrow * 32 + g) * 768 + e] = (bf16)o[j][r];
    }
  }
}

// ---------------- orchestration ----------------------------------------------
extern "C" void kernel_launch(void* const* d_in, const int* in_sizes, int n_in,
                              void* d_out, int out_size, void* d_ws, size_t ws_size,
                              hipStream_t stream)
{
  const float* input_nodes = (const float*)d_in[0];
  const float* attn_bias   = (const float*)d_in[1];
  const float* w_in   = (const float*)d_in[2];
  const float* b_in   = (const float*)d_in[3];
  const float* w_out  = (const float*)d_in[4];
  const float* b_out  = (const float*)d_in[5];
  const float* ln1_s  = (const float*)d_in[6];
  const float* ln1_b  = (const float*)d_in[7];
  const float* fc1_w  = (const float*)d_in[8];
  const float* fc1_bv = (const float*)d_in[9];
  const float* fc2_w  = (const float*)d_in[10];
  const float* fc2_bv = (const float*)d_in[11];
  const float* ln2_s  = (const float*)d_in[12];
  const float* ln2_b  = (const float*)d_in[13];
  float* out = (float*)d_out;

  char* ws = (char*)d_ws;
  // region layout (bytes), total 215,482,368:
  float* x2  = (float*)(ws);                    // 50,331,648   x after attn+resid
  bf16*  qkv = (bf16*)(ws + 50331648);          // 75,497,472   (region 100,663,296, reused by h)
  bf16*  h   = (bf16*)(ws + 50331648);          //              FC1 output (after qkv dead)
  bf16*  xln = (bf16*)(ws + 150994944);         // 25,165,824   xln -> attnout -> yln
  bf16*  Vt  = (bf16*)(ws + 176160768);         // 25,165,824
  bf16*  wbf = (bf16*)(ws + 201326592);         // 14,155,776   bf16 weights
  bf16* w_in_b  = wbf;
  bf16* w_out_b = wbf + 1769472;
  bf16* fc1_wb  = wbf + 2359296;
  bf16* fc2_wb  = wbf + 4718592;

  cvt_w<<<6912, 256, 0, stream>>>(w_in, w_out, fc1_w, fc2_w, w_in_b, w_out_b, fc1_wb, fc2_wb);
  ln_bf16<<<16384, 256, 0, stream>>>(input_nodes, ln1_s, ln1_b, xln);
  gemm_bt<0><<<dim3(18, 128), 256, 0, stream>>>(xln, w_in_b, b_in, nullptr, qkv, 16384, 2304, 768);
  v_transpose<<<dim3(8, 384), 256, 0, stream>>>(qkv, Vt);
  attn_fused<<<dim3(8, 384), 256, 0, stream>>>(qkv, Vt, attn_bias, xln);
  gemm_bt<1><<<dim3(6, 128), 256, 0, stream>>>(xln, w_out_b, b_out, input_nodes, x2, 16384, 768, 768);
  ln_bf16<<<16384, 256, 0, stream>>>(x2, ln2_s, ln2_b, xln);
  gemm_bt<2><<<dim3(24, 128), 256, 0, stream>>>(xln, fc1_wb, fc1_bv, nullptr, h, 16384, 3072, 768);
  gemm_bt<1><<<dim3(6, 128), 256, 0, stream>>>(h, fc2_wb, fc2_bv, x2, out, 16384, 768, 3072);
}